// Round 22
// baseline (181.795 us; speedup 1.0000x reference)
//
#include <hip/hip_runtime.h>
#include <cstdint>
#include <cstddef>

#define N_NODES 12288
#define B_EX    64
#define R_REG   36
#define E_EDGES 196608
#define DD_IN   512
#define DD_OUT  512
#define P_DIM   256
#define D_IMG   1024
#define TANH_C  2.885390081777927f   // 2*log2(e)
#define MAXD    128                  // max in-degree bound (Poisson(16); P(>128)~0)

// A2 concatenated GEMM operand: [12288][1024] bf16 : neigh | h1
#define A2_LD     1024
#define NEIGH_OFF 0
#define H1_OFF    512

typedef unsigned short ushort;
typedef __bf16 bf16x8 __attribute__((ext_vector_type(8)));
typedef float f32x4 __attribute__((ext_vector_type(4)));
typedef ushort ushort4v __attribute__((ext_vector_type(4)));
typedef ushort ushort8v __attribute__((ext_vector_type(8)));

__device__ __forceinline__ ushort f2bf(float f) {
    uint32_t u = __float_as_uint(f);
    uint32_t r = (u + 0x7fffu + ((u >> 16) & 1u)) >> 16;
    return (ushort)r;
}
__device__ __forceinline__ float bf2f(ushort u) {
    return __uint_as_float(((uint32_t)u) << 16);
}
__device__ __forceinline__ void gload_lds16(const void* g, void* l) {
    __builtin_amdgcn_global_load_lds((const __attribute__((address_space(1))) void*)g,
                                     (__attribute__((address_space(3))) void*)l, 16, 0, 0);
}
// reg-staged f32 -> bf16 LDS fill (used only in small/latency-tolerant GEMMs)
__device__ __forceinline__ void stage_f32(const float* __restrict__ src, void* ldsDst) {
    float4 v0 = *(const float4*)src;
    float4 v1 = *(const float4*)(src + 4);
    ushort8v o;
    o[0] = f2bf(v0.x); o[1] = f2bf(v0.y); o[2] = f2bf(v0.z); o[3] = f2bf(v0.w);
    o[4] = f2bf(v1.x); o[5] = f2bf(v1.y); o[6] = f2bf(v1.z); o[7] = f2bf(v1.w);
    *(ushort8v*)ldsDst = o;
}
__device__ __forceinline__ float fexp2(float x) {
    float r; asm("v_exp_f32 %0, %1" : "=v"(r) : "v"(x)); return r;
}
__device__ __forceinline__ float frcp(float x) {
    float r; asm("v_rcp_f32 %0, %1" : "=v"(r) : "v"(x)); return r;
}
// exp2 of clamped tanh-scaled argument (tanh saturates beyond |x|~29, lossless clamp)
__device__ __forceinline__ float exp2c(float x) {
    return fexp2(fminf(fmaxf(x, -30.f), 30.f));
}
// bijective XCD swizzle for nwg % 8 == 0 (identity otherwise)
__device__ __forceinline__ int xcd_swz(int lin, int nwg) {
    if ((nwg & 7) == 0) return (lin & 7) * (nwg >> 3) + (lin >> 3);
    return lin;
}

// ======== k1 preamble: h cvt + weight transposes + zero cur ========
#define PCVT_BLKS (N_NODES * DD_IN / 4 / 256)   // 6144
#define TR_BLKS   352
#define ZERO_INTS N_NODES                       // cur = 12288
#define ZERO_BLKS (ZERO_INTS / 256)             // 48
__global__ __launch_bounds__(256) void preamble(
    const float* __restrict__ h, ushort* __restrict__ h_bf,
    const float* __restrict__ Wf, const float* __restrict__ Wn,
    const float* __restrict__ Wi, const float* __restrict__ Wap,
    ushort* __restrict__ WfnT, ushort* __restrict__ WiZT,
    ushort* __restrict__ Wap1T, ushort* __restrict__ BT2,
    int* __restrict__ zero_p)
{
    if (blockIdx.x < PCVT_BLKS) {
        int i = blockIdx.x * 256 + threadIdx.x;
        float4 v = ((const float4*)h)[i];
        ushort4v o;
        o[0] = f2bf(v.x); o[1] = f2bf(v.y); o[2] = f2bf(v.z); o[3] = f2bf(v.w);
        ((ushort4v*)h_bf)[i] = o;
        return;
    }
    if (blockIdx.x >= PCVT_BLKS + TR_BLKS) {
        int i = (blockIdx.x - PCVT_BLKS - TR_BLKS) * 256 + threadIdx.x;
        if (i < ZERO_INTS) zero_p[i] = 0;
        return;
    }
    int t = blockIdx.x - PCVT_BLKS;
    const float* W; ushort* WT; int N, ldt, gx;
    if (t < 32)       { W = Wf;  WT = WfnT;                        N = 256; ldt = 512;  gx = 4; }
    else if (t < 96)  { W = Wn;  WT = WfnT + 256 * 512;            N = 512; ldt = 512;  gx = 8; t -= 32; }
    else if (t < 160) { W = Wi;  WT = WiZT;                        N = 256; ldt = 1024; gx = 4; t -= 96; }
    else if (t < 224) { W = Wap; WT = Wap1T;                       N = 512; ldt = 512;  gx = 8; t -= 160; }
    else if (t < 288) { W = Wap; WT = BT2 + NEIGH_OFF;             N = 512; ldt = 1024; gx = 8; t -= 224; }
    else              { W = Wap + 512 * 512; WT = BT2 + H1_OFF;    N = 512; ldt = 1024; gx = 8; t -= 288; }
    const int n0 = (t % gx) * 64, k0 = (t / gx) * 64;

    __shared__ float tt[64][65];
    const int tx = threadIdx.x & 15, ty = threadIdx.x >> 4;
#pragma unroll
    for (int r = 0; r < 4; ++r) {
        float4 v = *(const float4*)&W[(size_t)(k0 + ty * 4 + r) * N + n0 + tx * 4];
        tt[ty * 4 + r][tx * 4 + 0] = v.x;
        tt[ty * 4 + r][tx * 4 + 1] = v.y;
        tt[ty * 4 + r][tx * 4 + 2] = v.z;
        tt[ty * 4 + r][tx * 4 + 3] = v.w;
    }
    __syncthreads();
    const int nl = threadIdx.x >> 2, kq = (threadIdx.x & 3) * 16;
    ushort u[16] __attribute__((aligned(16)));
#pragma unroll
    for (int c = 0; c < 16; ++c) u[c] = f2bf(tt[kq + c][nl]);
    ushort* d = &WT[(size_t)(n0 + nl) * ldt + k0 + kq];
    *(ushort8v*)d = *(ushort8v*)&u[0];
    *(ushort8v*)(d + 8) = *(ushort8v*)&u[8];
}

// ======== k2: direct edge scatter (0..767) || batch sort (768) || wp GEMM (769..800) ====
#define ECNT_BLKS (E_EDGES / 256)   // 768
__global__ __launch_bounds__(256) void k2_scatter_sort_wp(
    const int* __restrict__ src, const int* __restrict__ dst,
    const int* __restrict__ bid,
    int* __restrict__ cur, int* __restrict__ ssrc2, int* __restrict__ nlist,
    const ushort* __restrict__ Wap1T, const float* __restrict__ Wim,
    ushort* __restrict__ WiZT)
{
    __shared__ ushort As[128 * 64];
    __shared__ ushort Bs[128 * 64];
    if (blockIdx.x < ECNT_BLKS) {
        int i = blockIdx.x * 256 + threadIdx.x;
        int d = dst[i];
        int p = atomicAdd(&cur[d], 1);
        if (p < MAXD) ssrc2[(size_t)d * MAXD + p] = src[i];
        return;
    }
    if (blockIdx.x == ECNT_BLKS) {
        __shared__ int bc[B_EX];
        __shared__ int bo[B_EX];
        if (threadIdx.x < B_EX) bc[threadIdx.x] = 0;
        __syncthreads();
        for (int i = threadIdx.x; i < N_NODES; i += 256)
            atomicAdd(&bc[bid[i]], 1);
        __syncthreads();
        if (threadIdx.x == 0) {
            int acc = 0;
            for (int i = 0; i < B_EX; ++i) { bo[i] = acc; acc += bc[i]; }
        }
        __syncthreads();
        if (threadIdx.x < B_EX) bc[threadIdx.x] = 0;   // reuse as cursor
        __syncthreads();
        for (int i = threadIdx.x; i < N_NODES; i += 256) {
            int b = bid[i];
            int p = bo[b] + atomicAdd(&bc[b], 1);
            nlist[p] = i;
        }
        return;
    }
    // ---- wp GEMM: W'^T = Wap1T @ Wim^T -> WiZT rows 256..767 ----
    const int K = DD_IN;
    const int tid = threadIdx.x;
    const int lane = tid & 63;
    const int wid = tid >> 6;
    const int wm = wid >> 1, wn = wid & 1;
    const int lin = blockIdx.x - (ECNT_BLKS + 1);
    const int m0 = (lin >> 3) * 128, n0 = (lin & 7) * 128;

    f32x4 acc[4][4] = {};
    const int srow = tid >> 3;
    const int schk = tid & 7;
    const char* AsB = (const char*)As;
    const char* BsB = (const char*)Bs;

    for (int k0 = 0; k0 < K; k0 += 64) {
#pragma unroll
        for (int i = 0; i < 4; ++i) {
            int row = i * 32 + srow;
            int ca = (schk ^ (row & 7)) * 8;
            gload_lds16(Wap1T + (size_t)(m0 + row) * K + k0 + ca,
                        (char*)As + i * 4096 + wid * 1024);
            stage_f32(Wim + (size_t)(n0 + row) * K + k0 + ca,
                      (char*)Bs + i * 4096 + wid * 1024 + lane * 16);
        }
        __syncthreads();
#pragma unroll
        for (int kk = 0; kk < 2; ++kk) {
            const int kc = kk * 4 + (lane >> 4);
            bf16x8 af[4], bfr[4];
#pragma unroll
            for (int i = 0; i < 4; ++i) {
                int row = wm * 64 + i * 16 + (lane & 15);
                af[i] = *(const bf16x8*)(AsB + row * 128 + ((kc ^ (row & 7)) << 4));
            }
#pragma unroll
            for (int j = 0; j < 4; ++j) {
                int col = wn * 64 + j * 16 + (lane & 15);
                bfr[j] = *(const bf16x8*)(BsB + col * 128 + ((kc ^ (col & 7)) << 4));
            }
#pragma unroll
            for (int i = 0; i < 4; ++i)
#pragma unroll
                for (int j = 0; j < 4; ++j)
                    acc[i][j] = __builtin_amdgcn_mfma_f32_16x16x32_bf16(af[i], bfr[j], acc[i][j], 0, 0, 0);
        }
        __syncthreads();
    }

#pragma unroll
    for (int i = 0; i < 4; ++i)
#pragma unroll
        for (int j = 0; j < 4; ++j)
#pragma unroll
            for (int q = 0; q < 4; ++q) {
                int row = m0 + wm * 64 + i * 16 + (lane >> 4) * 4 + q;   // W' col
                int col = n0 + wn * 64 + j * 16 + (lane & 15);           // W' row
                WiZT[(size_t)(256 + row) * D_IMG + col] = f2bf(acc[i][j][q]);
            }
}

// ======== k3: bprime (0,1) || imgz GEMM (2..109) || ff GEMM (110..1261) ========
// Epilogues store EXP2 of the tanh-scaled projections:
//   node_proj_s = exp2(clamp((acc+bf)*TANH_C))  (f32)
//   img_projb   = bf16(exp2(clamp((acc+bi)*TANH_C)))
#define IMGZ_BASE 2
#define FF_BASE   110
__global__ __launch_bounds__(256) void k3_imgz_ff(
    const float* __restrict__ bim, const float* __restrict__ Wap,
    const float* __restrict__ bap, float* __restrict__ bp,
    const float* __restrict__ imgf, const ushort* __restrict__ WiZT,
    const float* __restrict__ bi, ushort* __restrict__ img_projb,
    ushort* __restrict__ Z,
    const ushort* __restrict__ h_bf, const ushort* __restrict__ WfnT,
    const float* __restrict__ biasF, const float* __restrict__ biasN,
    float* __restrict__ node_proj_s, ushort* __restrict__ A2)
{
    __shared__ ushort As[128 * 64];
    __shared__ ushort Bs[128 * 64];
    const int t = threadIdx.x;
    if (blockIdx.x < IMGZ_BASE) {
        int n = blockIdx.x * 256 + t;
        float s = bap[n];
        for (int k = 0; k < DD_OUT; ++k) s += bim[k] * Wap[(size_t)k * DD_OUT + n];
        bp[n] = s;
        return;
    }
    const int lane = t & 63;
    const int wid = t >> 6;
    if (blockIdx.x < FF_BASE) {
        // ---- imgz GEMM: [img_projb | Z] = img_feats @ [Wi | W'] ----
        const int K = D_IMG;
        const int wm = wid >> 1, wn = wid & 1;
        const int lin = blockIdx.x - IMGZ_BASE;
        const int m0 = (lin / 6) * 128, n0 = (lin % 6) * 128;

        f32x4 acc[4][4] = {};
        const int srow = t >> 3;
        const int schk = t & 7;
        const char* AsB = (const char*)As;
        const char* BsB = (const char*)Bs;

        for (int k0 = 0; k0 < K; k0 += 64) {
#pragma unroll
            for (int i = 0; i < 4; ++i) {
                int row = i * 32 + srow;
                int ca = (schk ^ (row & 7)) * 8;
                stage_f32(imgf + (size_t)(m0 + row) * K + k0 + ca,
                          (char*)As + i * 4096 + wid * 1024 + lane * 16);
                gload_lds16(WiZT + (size_t)(n0 + row) * K + k0 + ca,
                            (char*)Bs + i * 4096 + wid * 1024);
            }
            __syncthreads();
#pragma unroll
            for (int kk = 0; kk < 2; ++kk) {
                const int kc = kk * 4 + (lane >> 4);
                bf16x8 af[4], bfr[4];
#pragma unroll
                for (int i = 0; i < 4; ++i) {
                    int row = wm * 64 + i * 16 + (lane & 15);
                    af[i] = *(const bf16x8*)(AsB + row * 128 + ((kc ^ (row & 7)) << 4));
                }
#pragma unroll
                for (int j = 0; j < 4; ++j) {
                    int col = wn * 64 + j * 16 + (lane & 15);
                    bfr[j] = *(const bf16x8*)(BsB + col * 128 + ((kc ^ (col & 7)) << 4));
                }
#pragma unroll
                for (int i = 0; i < 4; ++i)
#pragma unroll
                    for (int j = 0; j < 4; ++j)
                        acc[i][j] = __builtin_amdgcn_mfma_f32_16x16x32_bf16(af[i], bfr[j], acc[i][j], 0, 0, 0);
            }
            __syncthreads();
        }

        if (n0 < 256) {
#pragma unroll
            for (int i = 0; i < 4; ++i)
#pragma unroll
                for (int j = 0; j < 4; ++j)
#pragma unroll
                    for (int q = 0; q < 4; ++q) {
                        int row = m0 + wm * 64 + i * 16 + (lane >> 4) * 4 + q;
                        int col = n0 + wn * 64 + j * 16 + (lane & 15);
                        img_projb[(size_t)row * P_DIM + col] =
                            f2bf(exp2c((acc[i][j][q] + bi[col]) * TANH_C));
                    }
        } else {
#pragma unroll
            for (int i = 0; i < 4; ++i)
#pragma unroll
                for (int j = 0; j < 4; ++j)
#pragma unroll
                    for (int q = 0; q < 4; ++q) {
                        int row = m0 + wm * 64 + i * 16 + (lane >> 4) * 4 + q;
                        int col = n0 - 256 + wn * 64 + j * 16 + (lane & 15);
                        Z[(size_t)row * DD_OUT + col] = f2bf(acc[i][j][q]);
                    }
        }
        return;
    }
    // ---- ff GEMM: BM=128, BN=64, 1152 blocks ----
    const int K = DD_IN;
    const int lin = xcd_swz(blockIdx.x - FF_BASE, 1152);
    const int m0 = (lin / 12) * 128, n0 = (lin % 12) * 64;

    f32x4 acc[2][4] = {};
    const int srow = t >> 3;
    const int schk = t & 7;
    const char* AsB = (const char*)As;
    const char* BsB = (const char*)Bs;

    for (int k0 = 0; k0 < K; k0 += 64) {
#pragma unroll
        for (int i = 0; i < 4; ++i) {
            int row = i * 32 + srow;
            int ca = (schk ^ (row & 7)) * 8;
            gload_lds16(h_bf + (size_t)(m0 + row) * K + k0 + ca,
                        (char*)As + i * 4096 + wid * 1024);
        }
#pragma unroll
        for (int i = 0; i < 2; ++i) {
            int row = i * 32 + srow;
            int cb = (schk ^ (row & 7)) * 8;
            gload_lds16(WfnT + (size_t)(n0 + row) * K + k0 + cb,
                        (char*)Bs + i * 4096 + wid * 1024);
        }
        __syncthreads();
#pragma unroll
        for (int kk = 0; kk < 2; ++kk) {
            const int kc = kk * 4 + (lane >> 4);
            bf16x8 af[2], bfr[4];
#pragma unroll
            for (int i = 0; i < 2; ++i) {
                int row = wid * 32 + i * 16 + (lane & 15);
                af[i] = *(const bf16x8*)(AsB + row * 128 + ((kc ^ (row & 7)) << 4));
            }
#pragma unroll
            for (int j = 0; j < 4; ++j) {
                int col = j * 16 + (lane & 15);
                bfr[j] = *(const bf16x8*)(BsB + col * 128 + ((kc ^ (col & 7)) << 4));
            }
#pragma unroll
            for (int i = 0; i < 2; ++i)
#pragma unroll
                for (int j = 0; j < 4; ++j)
                    acc[i][j] = __builtin_amdgcn_mfma_f32_16x16x32_bf16(af[i], bfr[j], acc[i][j], 0, 0, 0);
        }
        __syncthreads();
    }

    if (n0 < 256) {
#pragma unroll
        for (int i = 0; i < 2; ++i)
#pragma unroll
            for (int j = 0; j < 4; ++j)
#pragma unroll
                for (int q = 0; q < 4; ++q) {
                    int row = m0 + wid * 32 + i * 16 + (lane >> 4) * 4 + q;
                    int col = n0 + j * 16 + (lane & 15);
                    node_proj_s[(size_t)row * P_DIM + col] =
                        exp2c((acc[i][j][q] + biasF[col]) * TANH_C);
                }
    } else {
#pragma unroll
        for (int i = 0; i < 2; ++i)
#pragma unroll
            for (int j = 0; j < 4; ++j)
#pragma unroll
                for (int q = 0; q < 4; ++q) {
                    int row = m0 + wid * 32 + i * 16 + (lane >> 4) * 4 + q;
                    int col = n0 - 256 + j * 16 + (lane & 15);
                    A2[(size_t)row * A2_LD + H1_OFF + col] = f2bf(acc[i][j][q] + biasN[col]);
                }
    }
}

// ======== k4: att+imgz, block-cooperative LDS staging ========
// Block = 512 threads (8 waves), 16 nodes (nlist order, mostly one batch).
// Stage Eip[b0] (18KB) + Z[b0] (36KB) in LDS once; each wave computes 2 nodes
// from LDS. ~8% straddling nodes fall back to global loads.
#define K4_NPB 16
__global__ __launch_bounds__(512) void k4_att(
    const float* __restrict__ Enp, const ushort* __restrict__ Eip,
    const int* __restrict__ batch_ids, const float* __restrict__ Wa,
    const ushort* __restrict__ Z, ushort* __restrict__ imgz,
    const int* __restrict__ nlist)
{
    __shared__ ushort eip_s[R_REG * P_DIM];   // 18 KB
    __shared__ ushort z_s[R_REG * DD_OUT];    // 36 KB
    __shared__ float red[8][R_REG][20];       // 22.5 KB
    const int tid = threadIdx.x;
    const int lane = tid & 63;
    const int wv = tid >> 6;
    const int base = blockIdx.x * K4_NPB;
    const int b0 = batch_ids[nlist[base]];

    // ---- stage batch slabs ----
    {
        const ushort8v* se = (const ushort8v*)(Eip + (size_t)b0 * R_REG * P_DIM);
        ushort8v* de = (ushort8v*)eip_s;
        for (int i = tid; i < R_REG * P_DIM / 8; i += 512) de[i] = se[i];
        const ushort8v* sz = (const ushort8v*)(Z + (size_t)b0 * R_REG * DD_OUT);
        ushort8v* dz = (ushort8v*)z_s;
        for (int i = tid; i < R_REG * DD_OUT / 8; i += 512) dz[i] = sz[i];
    }
    __syncthreads();

    const float4 wa = *(const float4*)(Wa + 4 * lane);

    for (int j = 0; j < 2; ++j) {
        const int n = nlist[base + wv * 2 + j];
        const int b = batch_ids[n];
        const float4 en = *(const float4*)(Enp + (size_t)n * P_DIM + 4 * lane);
        const bool inlds = (b == b0);

        auto region = [&](int r, ushort4v ip) {
            float u0 = fmaf(en.x, bf2f(ip[0]), 1.f);
            float u1 = fmaf(en.y, bf2f(ip[1]), 1.f);
            float u2 = fmaf(en.z, bf2f(ip[2]), 1.f);
            float u3 = fmaf(en.w, bf2f(ip[3]), 1.f);
            float p01 = u0 * u1, p23 = u2 * u3;
            float n01 = fmaf(wa.x, u1, wa.y * u0);
            float n23 = fmaf(wa.z, u3, wa.w * u2);
            float N = fmaf(n01, p23, n23 * p01);
            float p = N * frcp(p01 * p23);
            p += __shfl_xor(p, 16);
            p += __shfl_xor(p, 32);
            if (lane < 16) red[wv][r][lane] = p;
        };
        if (inlds) {
#pragma unroll
            for (int r = 0; r < R_REG; ++r)
                region(r, *(const ushort4v*)(eip_s + r * P_DIM + 4 * lane));
        } else {
            const ushort* ip0 = Eip + (size_t)b * R_REG * P_DIM + 4 * lane;
#pragma unroll
            for (int r = 0; r < R_REG; ++r)
                region(r, *(const ushort4v*)(ip0 + (size_t)r * P_DIM));
        }
        // (red[wv] is wave-private; within-wave lgkmcnt ordering suffices)

        float logit = -INFINITY;
        if (lane < R_REG) {
            const float* row = &red[wv][lane][0];
            float4 a = *(const float4*)row;
            float4 bq = *(const float4*)(row + 4);
            float4 c = *(const float4*)(row + 8);
            float4 d = *(const float4*)(row + 12);
            float s01 = ((a.x + a.y) + (a.z + a.w)) + ((bq.x + bq.y) + (bq.z + bq.w));
            float s23 = ((c.x + c.y) + (c.z + c.w)) + ((d.x + d.y) + (d.z + d.w));
            logit = -2.f * (s01 + s23);
        }
        float m = logit;
#pragma unroll
        for (int o = 32; o; o >>= 1) m = fmaxf(m, __shfl_xor(m, o));
        float e = (lane < R_REG) ? __expf(logit - m) : 0.f;
        float s = e;
#pragma unroll
        for (int o = 32; o; o >>= 1) s += __shfl_xor(s, o);
        float inv_s = frcp(s);
        if (lane < R_REG) red[wv][lane][16] = e * inv_s;

        // ---- imgz[n] = sum_r att[r] * Z[b][r][:]; lane owns 8 cols ----
        float az[8] = {};
        auto zstep = [&](int r, uint4 zv) {
            float a = red[wv][r][16];
            az[0] = fmaf(a, bf2f((ushort)(zv.x & 0xffffu)), az[0]);
            az[1] = fmaf(a, bf2f((ushort)(zv.x >> 16)),     az[1]);
            az[2] = fmaf(a, bf2f((ushort)(zv.y & 0xffffu)), az[2]);
            az[3] = fmaf(a, bf2f((ushort)(zv.y >> 16)),     az[3]);
            az[4] = fmaf(a, bf2f((ushort)(zv.z & 0xffffu)), az[4]);
            az[5] = fmaf(a, bf2f((ushort)(zv.z >> 16)),     az[5]);
            az[6] = fmaf(a, bf2f((ushort)(zv.w & 0xffffu)), az[6]);
            az[7] = fmaf(a, bf2f((ushort)(zv.w >> 16)),     az[7]);
        };
        if (inlds) {
#pragma unroll 4
            for (int r = 0; r < R_REG; ++r)
                zstep(r, *(const uint4*)(z_s + r * DD_OUT + lane * 8));
        } else {
            const ushort* zb = Z + (size_t)b * R_REG * DD_OUT + lane * 8;
#pragma unroll 4
            for (int r = 0; r < R_REG; ++r)
                zstep(r, *(const uint4*)(zb + (size_t)r * DD_OUT));
        }
        ushort8v zo;
#pragma unroll
        for (int i = 0; i < 8; ++i) zo[i] = f2bf(az[i]);
        *(ushort8v*)(imgz + (size_t)n * DD_OUT + lane * 8) = zo;
    }
}

// ======== k5: CSR gather (direct-scatter layout): wave per node, 4 loads in flight ====
__device__ __forceinline__ void acc8(float* a, uint4 v) {
    a[0] += bf2f((ushort)(v.x & 0xffffu)); a[1] += bf2f((ushort)(v.x >> 16));
    a[2] += bf2f((ushort)(v.y & 0xffffu)); a[3] += bf2f((ushort)(v.y >> 16));
    a[4] += bf2f((ushort)(v.z & 0xffffu)); a[5] += bf2f((ushort)(v.z >> 16));
    a[6] += bf2f((ushort)(v.w & 0xffffu)); a[7] += bf2f((ushort)(v.w >> 16));
}

__global__ __launch_bounds__(256) void k5_gather(
    const int* __restrict__ cur, const int* __restrict__ ssrc2,
    const ushort* __restrict__ A2h1, ushort* __restrict__ A2nb)
{
    const int lane = threadIdx.x & 63;
    const int wv = threadIdx.x >> 6;
    const int n = blockIdx.x * 4 + wv;
    int dcnt = cur[n];
    if (dcnt > MAXD) dcnt = MAXD;
    const int* es = ssrc2 + (size_t)n * MAXD;

    float a[8] = {};
    int e = 0;
    for (; e + 4 <= dcnt; e += 4) {
        int s0 = es[e], s1 = es[e + 1], s2 = es[e + 2], s3 = es[e + 3];
        uint4 v0 = *(const uint4*)(A2h1 + (size_t)s0 * A2_LD + lane * 8);
        uint4 v1 = *(const uint4*)(A2h1 + (size_t)s1 * A2_LD + lane * 8);
        uint4 v2 = *(const uint4*)(A2h1 + (size_t)s2 * A2_LD + lane * 8);
        uint4 v3 = *(const uint4*)(A2h1 + (size_t)s3 * A2_LD + lane * 8);
        acc8(a, v0); acc8(a, v1); acc8(a, v2); acc8(a, v3);
    }
    for (; e < dcnt; ++e) {
        int s0 = es[e];
        uint4 v0 = *(const uint4*)(A2h1 + (size_t)s0 * A2_LD + lane * 8);
        acc8(a, v0);
    }
    ushort8v o;
#pragma unroll
    for (int i = 0; i < 8; ++i) o[i] = f2bf(a[i]);
    *(ushort8v*)(A2nb + (size_t)n * A2_LD + lane * 8) = o;
}

// ======== k6: final GEMM: out = relu(A2 @ BT2^T + imgz + b'), BM=128 BN=64, K=1024 ====
__global__ __launch_bounds__(256) void gemm_out(
    const ushort* __restrict__ A, const ushort* __restrict__ BT,
    const float* __restrict__ bias, const ushort* __restrict__ Cadd,
    float* __restrict__ Cf)
{
    __shared__ ushort As[128 * 64];
    __shared__ ushort Bs[64 * 64];
    const int K = A2_LD;
    const int tid = threadIdx.x;
    const int lane = tid & 63;
    const int wid = tid >> 6;
    const int lin = xcd_swz(blockIdx.y * 8 + blockIdx.x, 768);
    const int m0 = (lin >> 3) * 128, n0 = (lin & 7) * 64;

    f32x4 acc[2][4] = {};
    const int srow = tid >> 3;
    const int schk = tid & 7;
    const char* AsB = (const char*)As;
    const char* BsB = (const char*)Bs;

    for (int k0 = 0; k0 < K; k0 += 64) {
#pragma unroll
        for (int i = 0; i < 4; ++i) {
            int row = i * 32 + srow;
            int ca = (schk ^ (row & 7)) * 8;
            gload_lds16(A + (size_t)(m0 + row) * K + k0 + ca,
                        (char*)As + i * 4096 + wid * 1024);
        }
#pragma unroll
        for (int i = 0; i < 2; ++i) {
            int row = i * 32 + srow;
            int cb = (schk ^ (row & 7)) * 8;
            gload_lds16(BT + (size_t)(n0 + row) * K + k0 + cb,
                        (char*)Bs + i * 4096 + wid * 1024);
        }
        __syncthreads();
#pragma unroll
        for (int kk = 0; kk < 2; ++kk) {
            const int kc = kk * 4 + (lane >> 4);
            bf16x8 af[2], bfr[4];
#pragma unroll
            for (int i = 0; i < 2; ++i) {
                int row = wid * 32 + i * 16 + (lane & 15);
                af[i] = *(const bf16x8*)(AsB + row * 128 + ((kc ^ (row & 7)) << 4));
            }
#pragma unroll
            for (int j = 0; j < 4; ++j) {
                int col = j * 16 + (lane & 15);
                bfr[j] = *(const bf16x8*)(BsB + col * 128 + ((kc ^ (col & 7)) << 4));
            }
#pragma unroll
            for (int i = 0; i < 2; ++i)
#pragma unroll
                for (int j = 0; j < 4; ++j)
                    acc[i][j] = __builtin_amdgcn_mfma_f32_16x16x32_bf16(af[i], bfr[j], acc[i][j], 0, 0, 0);
        }
        __syncthreads();
    }

#pragma unroll
    for (int i = 0; i < 2; ++i)
#pragma unroll
        for (int j = 0; j < 4; ++j)
#pragma unroll
            for (int q = 0; q < 4; ++q) {
                int row = m0 + wid * 32 + i * 16 + (lane >> 4) * 4 + q;
                int col = n0 + j * 16 + (lane & 15);
                float v = acc[i][j][q] + bias[col] + bf2f(Cadd[(size_t)row * DD_OUT + col]);
                Cf[(size_t)row * DD_OUT + col] = fmaxf(v, 0.f);
            }
}

extern "C" void kernel_launch(void* const* d_in, const int* in_sizes, int n_in,
                              void* d_out, int out_size, void* d_ws, size_t ws_size,
                              hipStream_t stream) {
    const float* h         = (const float*)d_in[0];
    const float* img_feats = (const float*)d_in[1];
    const int*   batch_ids = (const int*)d_in[2];
    const int*   src       = (const int*)d_in[3];
    const int*   dst       = (const int*)d_in[4];
    const float* Wf  = (const float*)d_in[5];
    const float* bf  = (const float*)d_in[6];
    const float* Wi  = (const float*)d_in[7];
    const float* bi  = (const float*)d_in[8];
    const float* Wa  = (const float*)d_in[9];
    // d_in[10] = ba: constant logit shift, cancels in softmax
    const float* Wn  = (const float*)d_in[11];
    const float* bn  = (const float*)d_in[12];
    const float* Wim = (const float*)d_in[13];
    const float* bim = (const float*)d_in[14];
    const float* Wap = (const float*)d_in[15];
    const float* bap = (const float*)d_in[16];
    float* out = (float*)d_out;
    float* ws  = (float*)d_ws;

    // ---- workspace layout (offsets in 4-byte words) ----
    ushort* A2      = (ushort*)(ws + 0);          // [12288][1024] bf16: neigh|h1
    ushort* imgz    = (ushort*)(ws + 6291456);    // [12288][512] bf16
    float*  node_proj = ws + 9437184;             // [12288][256] f32 = Enp (exp2 form)
    ushort* img_projb = (ushort*)(ws + 12582912); // [2304][256] bf16 = Eip (exp2 form)
    ushort* Z      = (ushort*)(ws + 12877824);    // [2304][512] bf16
    ushort* h_bf   = (ushort*)(ws + 13467648);    // [12288][512] bf16
    ushort* WfnT   = (ushort*)(ws + 16613376);    // [768][512] bf16
    ushort* WiZT   = (ushort*)(ws + 16809984);    // [768][1024] bf16: Wi^T | W'^T
    ushort* Wap1T  = (ushort*)(ws + 17203200);    // [512][512] bf16
    ushort* BT2    = (ushort*)(ws + 17334272);    // [512][1024] bf16: Wap1^T | Wap2^T
    float*  bprime = ws + 17596416;               // [512]
    int* cur   = (int*)(ws + 17596928);           // [12288] (zeroed; becomes degree)
    int* nlist = cur + N_NODES;                   // [12288]
    int* ssrc2 = nlist + N_NODES;                 // [12288 * MAXD]

    dim3 blk(256);

    // k1: h cvt + weight transposes + zero cur
    preamble<<<dim3(PCVT_BLKS + TR_BLKS + ZERO_BLKS), blk, 0, stream>>>(
        h, h_bf, Wf, Wn, Wi, Wap, WfnT, WiZT, Wap1T, BT2, cur);
    // k2: direct edge scatter || batch sort -> nlist || wp GEMM
    k2_scatter_sort_wp<<<dim3(ECNT_BLKS + 1 + 32), blk, 0, stream>>>(
        src, dst, batch_ids, cur, ssrc2, nlist, Wap1T, Wim, WiZT);
    // k3: bprime || imgz GEMM (exp2 epilogue) || ff GEMM (exp2 epilogue)
    k3_imgz_ff<<<dim3(FF_BASE + 1152), blk, 0, stream>>>(
        bim, Wap, bap, bprime,
        img_feats, WiZT, bi, img_projb, Z,
        h_bf, WfnT, bf, bn, node_proj, A2);
    // k4: att+imgz (block-cooperative LDS staging, 16 nodes/block)
    k4_att<<<dim3(N_NODES / K4_NPB), dim3(512), 0, stream>>>(
        node_proj, img_projb, batch_ids, Wa, Z, imgz, nlist);
    // k5: CSR gather -> A2 neigh cols
    k5_gather<<<dim3(N_NODES / 4), blk, 0, stream>>>(
        cur, ssrc2, A2 + H1_OFF, A2 + NEIGH_OFF);
    // k6: out = relu(A2 @ [Wap1; Wap2] + imgz + b')
    gemm_out<<<dim3(8, 96), blk, 0, stream>>>(A2, BT2, bprime, imgz, out);
}

// Round 23
// 173.184 us; speedup vs baseline: 1.0497x; 1.0497x over previous
//
#include <hip/hip_runtime.h>
#include <cstdint>
#include <cstddef>

#define N_NODES 12288
#define B_EX    64
#define R_REG   36
#define E_EDGES 196608
#define DD_IN   512
#define DD_OUT  512
#define P_DIM   256
#define D_IMG   1024
#define TANH_C  2.885390081777927f   // 2*log2(e)
#define MAXD    128                  // max in-degree bound (Poisson(16); P(>128)~0)

// A2 concatenated GEMM operand: [12288][1024] bf16 : neigh | h1
#define A2_LD     1024
#define NEIGH_OFF 0
#define H1_OFF    512

typedef unsigned short ushort;
typedef __bf16 bf16x8 __attribute__((ext_vector_type(8)));
typedef float f32x4 __attribute__((ext_vector_type(4)));
typedef ushort ushort4v __attribute__((ext_vector_type(4)));
typedef ushort ushort8v __attribute__((ext_vector_type(8)));

__device__ __forceinline__ ushort f2bf(float f) {
    uint32_t u = __float_as_uint(f);
    uint32_t r = (u + 0x7fffu + ((u >> 16) & 1u)) >> 16;
    return (ushort)r;
}
__device__ __forceinline__ float bf2f(ushort u) {
    return __uint_as_float(((uint32_t)u) << 16);
}
__device__ __forceinline__ void gload_lds16(const void* g, void* l) {
    __builtin_amdgcn_global_load_lds((const __attribute__((address_space(1))) void*)g,
                                     (__attribute__((address_space(3))) void*)l, 16, 0, 0);
}
// reg-staged f32 -> bf16 LDS fill (used only in small/latency-tolerant GEMMs)
__device__ __forceinline__ void stage_f32(const float* __restrict__ src, void* ldsDst) {
    float4 v0 = *(const float4*)src;
    float4 v1 = *(const float4*)(src + 4);
    ushort8v o;
    o[0] = f2bf(v0.x); o[1] = f2bf(v0.y); o[2] = f2bf(v0.z); o[3] = f2bf(v0.w);
    o[4] = f2bf(v1.x); o[5] = f2bf(v1.y); o[6] = f2bf(v1.z); o[7] = f2bf(v1.w);
    *(ushort8v*)ldsDst = o;
}
__device__ __forceinline__ float fexp2(float x) {
    float r; asm("v_exp_f32 %0, %1" : "=v"(r) : "v"(x)); return r;
}
__device__ __forceinline__ float frcp(float x) {
    float r; asm("v_rcp_f32 %0, %1" : "=v"(r) : "v"(x)); return r;
}
// exp2 of clamped tanh-scaled argument (tanh saturates beyond |x|~29, lossless clamp)
__device__ __forceinline__ float exp2c(float x) {
    return fexp2(fminf(fmaxf(x, -30.f), 30.f));
}
// bijective XCD swizzle for nwg % 8 == 0 (identity otherwise)
__device__ __forceinline__ int xcd_swz(int lin, int nwg) {
    if ((nwg & 7) == 0) return (lin & 7) * (nwg >> 3) + (lin >> 3);
    return lin;
}

// ======== k1 preamble: h cvt + weight transposes + zero cur ========
#define PCVT_BLKS (N_NODES * DD_IN / 4 / 256)   // 6144
#define TR_BLKS   352
#define ZERO_INTS N_NODES                       // cur = 12288
#define ZERO_BLKS (ZERO_INTS / 256)             // 48
__global__ __launch_bounds__(256) void preamble(
    const float* __restrict__ h, ushort* __restrict__ h_bf,
    const float* __restrict__ Wf, const float* __restrict__ Wn,
    const float* __restrict__ Wi, const float* __restrict__ Wap,
    ushort* __restrict__ WfnT, ushort* __restrict__ WiZT,
    ushort* __restrict__ Wap1T, ushort* __restrict__ BT2,
    int* __restrict__ zero_p)
{
    if (blockIdx.x < PCVT_BLKS) {
        int i = blockIdx.x * 256 + threadIdx.x;
        float4 v = ((const float4*)h)[i];
        ushort4v o;
        o[0] = f2bf(v.x); o[1] = f2bf(v.y); o[2] = f2bf(v.z); o[3] = f2bf(v.w);
        ((ushort4v*)h_bf)[i] = o;
        return;
    }
    if (blockIdx.x >= PCVT_BLKS + TR_BLKS) {
        int i = (blockIdx.x - PCVT_BLKS - TR_BLKS) * 256 + threadIdx.x;
        if (i < ZERO_INTS) zero_p[i] = 0;
        return;
    }
    int t = blockIdx.x - PCVT_BLKS;
    const float* W; ushort* WT; int N, ldt, gx;
    if (t < 32)       { W = Wf;  WT = WfnT;                        N = 256; ldt = 512;  gx = 4; }
    else if (t < 96)  { W = Wn;  WT = WfnT + 256 * 512;            N = 512; ldt = 512;  gx = 8; t -= 32; }
    else if (t < 160) { W = Wi;  WT = WiZT;                        N = 256; ldt = 1024; gx = 4; t -= 96; }
    else if (t < 224) { W = Wap; WT = Wap1T;                       N = 512; ldt = 512;  gx = 8; t -= 160; }
    else if (t < 288) { W = Wap; WT = BT2 + NEIGH_OFF;             N = 512; ldt = 1024; gx = 8; t -= 224; }
    else              { W = Wap + 512 * 512; WT = BT2 + H1_OFF;    N = 512; ldt = 1024; gx = 8; t -= 288; }
    const int n0 = (t % gx) * 64, k0 = (t / gx) * 64;

    __shared__ float tt[64][65];
    const int tx = threadIdx.x & 15, ty = threadIdx.x >> 4;
#pragma unroll
    for (int r = 0; r < 4; ++r) {
        float4 v = *(const float4*)&W[(size_t)(k0 + ty * 4 + r) * N + n0 + tx * 4];
        tt[ty * 4 + r][tx * 4 + 0] = v.x;
        tt[ty * 4 + r][tx * 4 + 1] = v.y;
        tt[ty * 4 + r][tx * 4 + 2] = v.z;
        tt[ty * 4 + r][tx * 4 + 3] = v.w;
    }
    __syncthreads();
    const int nl = threadIdx.x >> 2, kq = (threadIdx.x & 3) * 16;
    ushort u[16] __attribute__((aligned(16)));
#pragma unroll
    for (int c = 0; c < 16; ++c) u[c] = f2bf(tt[kq + c][nl]);
    ushort* d = &WT[(size_t)(n0 + nl) * ldt + k0 + kq];
    *(ushort8v*)d = *(ushort8v*)&u[0];
    *(ushort8v*)(d + 8) = *(ushort8v*)&u[8];
}

// ======== k2: direct edge scatter (0..767) || batch sort (768) || wp GEMM (769..800) ====
#define ECNT_BLKS (E_EDGES / 256)   // 768
__global__ __launch_bounds__(256) void k2_scatter_sort_wp(
    const int* __restrict__ src, const int* __restrict__ dst,
    const int* __restrict__ bid,
    int* __restrict__ cur, int* __restrict__ ssrc2, int* __restrict__ nlist,
    const ushort* __restrict__ Wap1T, const float* __restrict__ Wim,
    ushort* __restrict__ WiZT)
{
    __shared__ ushort As[128 * 64];
    __shared__ ushort Bs[128 * 64];
    if (blockIdx.x < ECNT_BLKS) {
        int i = blockIdx.x * 256 + threadIdx.x;
        int d = dst[i];
        int p = atomicAdd(&cur[d], 1);
        if (p < MAXD) ssrc2[(size_t)d * MAXD + p] = src[i];
        return;
    }
    if (blockIdx.x == ECNT_BLKS) {
        __shared__ int bc[B_EX];
        __shared__ int bo[B_EX];
        if (threadIdx.x < B_EX) bc[threadIdx.x] = 0;
        __syncthreads();
        for (int i = threadIdx.x; i < N_NODES; i += 256)
            atomicAdd(&bc[bid[i]], 1);
        __syncthreads();
        if (threadIdx.x == 0) {
            int acc = 0;
            for (int i = 0; i < B_EX; ++i) { bo[i] = acc; acc += bc[i]; }
        }
        __syncthreads();
        if (threadIdx.x < B_EX) bc[threadIdx.x] = 0;   // reuse as cursor
        __syncthreads();
        for (int i = threadIdx.x; i < N_NODES; i += 256) {
            int b = bid[i];
            int p = bo[b] + atomicAdd(&bc[b], 1);
            nlist[p] = i;
        }
        return;
    }
    // ---- wp GEMM: W'^T = Wap1T @ Wim^T -> WiZT rows 256..767 ----
    const int K = DD_IN;
    const int tid = threadIdx.x;
    const int lane = tid & 63;
    const int wid = tid >> 6;
    const int wm = wid >> 1, wn = wid & 1;
    const int lin = blockIdx.x - (ECNT_BLKS + 1);
    const int m0 = (lin >> 3) * 128, n0 = (lin & 7) * 128;

    f32x4 acc[4][4] = {};
    const int srow = tid >> 3;
    const int schk = tid & 7;
    const char* AsB = (const char*)As;
    const char* BsB = (const char*)Bs;

    for (int k0 = 0; k0 < K; k0 += 64) {
#pragma unroll
        for (int i = 0; i < 4; ++i) {
            int row = i * 32 + srow;
            int ca = (schk ^ (row & 7)) * 8;
            gload_lds16(Wap1T + (size_t)(m0 + row) * K + k0 + ca,
                        (char*)As + i * 4096 + wid * 1024);
            stage_f32(Wim + (size_t)(n0 + row) * K + k0 + ca,
                      (char*)Bs + i * 4096 + wid * 1024 + lane * 16);
        }
        __syncthreads();
#pragma unroll
        for (int kk = 0; kk < 2; ++kk) {
            const int kc = kk * 4 + (lane >> 4);
            bf16x8 af[4], bfr[4];
#pragma unroll
            for (int i = 0; i < 4; ++i) {
                int row = wm * 64 + i * 16 + (lane & 15);
                af[i] = *(const bf16x8*)(AsB + row * 128 + ((kc ^ (row & 7)) << 4));
            }
#pragma unroll
            for (int j = 0; j < 4; ++j) {
                int col = wn * 64 + j * 16 + (lane & 15);
                bfr[j] = *(const bf16x8*)(BsB + col * 128 + ((kc ^ (col & 7)) << 4));
            }
#pragma unroll
            for (int i = 0; i < 4; ++i)
#pragma unroll
                for (int j = 0; j < 4; ++j)
                    acc[i][j] = __builtin_amdgcn_mfma_f32_16x16x32_bf16(af[i], bfr[j], acc[i][j], 0, 0, 0);
        }
        __syncthreads();
    }

#pragma unroll
    for (int i = 0; i < 4; ++i)
#pragma unroll
        for (int j = 0; j < 4; ++j)
#pragma unroll
            for (int q = 0; q < 4; ++q) {
                int row = m0 + wm * 64 + i * 16 + (lane >> 4) * 4 + q;   // W' col
                int col = n0 + wn * 64 + j * 16 + (lane & 15);           // W' row
                WiZT[(size_t)(256 + row) * D_IMG + col] = f2bf(acc[i][j][q]);
            }
}

// ======== k3: bprime (0,1) || imgz GEMM (2..109) || ff GEMM (110..1261) ========
// Epilogues store EXP2 of the tanh-scaled projections:
//   node_proj_s = exp2(clamp((acc+bf)*TANH_C))  (f32)
//   img_projb   = bf16(exp2(clamp((acc+bi)*TANH_C)))
#define IMGZ_BASE 2
#define FF_BASE   110
__global__ __launch_bounds__(256) void k3_imgz_ff(
    const float* __restrict__ bim, const float* __restrict__ Wap,
    const float* __restrict__ bap, float* __restrict__ bp,
    const float* __restrict__ imgf, const ushort* __restrict__ WiZT,
    const float* __restrict__ bi, ushort* __restrict__ img_projb,
    ushort* __restrict__ Z,
    const ushort* __restrict__ h_bf, const ushort* __restrict__ WfnT,
    const float* __restrict__ biasF, const float* __restrict__ biasN,
    float* __restrict__ node_proj_s, ushort* __restrict__ A2)
{
    __shared__ ushort As[128 * 64];
    __shared__ ushort Bs[128 * 64];
    const int t = threadIdx.x;
    if (blockIdx.x < IMGZ_BASE) {
        int n = blockIdx.x * 256 + t;
        float s = bap[n];
        for (int k = 0; k < DD_OUT; ++k) s += bim[k] * Wap[(size_t)k * DD_OUT + n];
        bp[n] = s;
        return;
    }
    const int lane = t & 63;
    const int wid = t >> 6;
    if (blockIdx.x < FF_BASE) {
        // ---- imgz GEMM: [img_projb | Z] = img_feats @ [Wi | W'] ----
        const int K = D_IMG;
        const int wm = wid >> 1, wn = wid & 1;
        const int lin = blockIdx.x - IMGZ_BASE;
        const int m0 = (lin / 6) * 128, n0 = (lin % 6) * 128;

        f32x4 acc[4][4] = {};
        const int srow = t >> 3;
        const int schk = t & 7;
        const char* AsB = (const char*)As;
        const char* BsB = (const char*)Bs;

        for (int k0 = 0; k0 < K; k0 += 64) {
#pragma unroll
            for (int i = 0; i < 4; ++i) {
                int row = i * 32 + srow;
                int ca = (schk ^ (row & 7)) * 8;
                stage_f32(imgf + (size_t)(m0 + row) * K + k0 + ca,
                          (char*)As + i * 4096 + wid * 1024 + lane * 16);
                gload_lds16(WiZT + (size_t)(n0 + row) * K + k0 + ca,
                            (char*)Bs + i * 4096 + wid * 1024);
            }
            __syncthreads();
#pragma unroll
            for (int kk = 0; kk < 2; ++kk) {
                const int kc = kk * 4 + (lane >> 4);
                bf16x8 af[4], bfr[4];
#pragma unroll
                for (int i = 0; i < 4; ++i) {
                    int row = wm * 64 + i * 16 + (lane & 15);
                    af[i] = *(const bf16x8*)(AsB + row * 128 + ((kc ^ (row & 7)) << 4));
                }
#pragma unroll
                for (int j = 0; j < 4; ++j) {
                    int col = wn * 64 + j * 16 + (lane & 15);
                    bfr[j] = *(const bf16x8*)(BsB + col * 128 + ((kc ^ (col & 7)) << 4));
                }
#pragma unroll
                for (int i = 0; i < 4; ++i)
#pragma unroll
                    for (int j = 0; j < 4; ++j)
                        acc[i][j] = __builtin_amdgcn_mfma_f32_16x16x32_bf16(af[i], bfr[j], acc[i][j], 0, 0, 0);
            }
            __syncthreads();
        }

        if (n0 < 256) {
#pragma unroll
            for (int i = 0; i < 4; ++i)
#pragma unroll
                for (int j = 0; j < 4; ++j)
#pragma unroll
                    for (int q = 0; q < 4; ++q) {
                        int row = m0 + wm * 64 + i * 16 + (lane >> 4) * 4 + q;
                        int col = n0 + wn * 64 + j * 16 + (lane & 15);
                        img_projb[(size_t)row * P_DIM + col] =
                            f2bf(exp2c((acc[i][j][q] + bi[col]) * TANH_C));
                    }
        } else {
#pragma unroll
            for (int i = 0; i < 4; ++i)
#pragma unroll
                for (int j = 0; j < 4; ++j)
#pragma unroll
                    for (int q = 0; q < 4; ++q) {
                        int row = m0 + wm * 64 + i * 16 + (lane >> 4) * 4 + q;
                        int col = n0 - 256 + wn * 64 + j * 16 + (lane & 15);
                        Z[(size_t)row * DD_OUT + col] = f2bf(acc[i][j][q]);
                    }
        }
        return;
    }
    // ---- ff GEMM: BM=128, BN=64, 1152 blocks ----
    const int K = DD_IN;
    const int lin = xcd_swz(blockIdx.x - FF_BASE, 1152);
    const int m0 = (lin / 12) * 128, n0 = (lin % 12) * 64;

    f32x4 acc[2][4] = {};
    const int srow = t >> 3;
    const int schk = t & 7;
    const char* AsB = (const char*)As;
    const char* BsB = (const char*)Bs;

    for (int k0 = 0; k0 < K; k0 += 64) {
#pragma unroll
        for (int i = 0; i < 4; ++i) {
            int row = i * 32 + srow;
            int ca = (schk ^ (row & 7)) * 8;
            gload_lds16(h_bf + (size_t)(m0 + row) * K + k0 + ca,
                        (char*)As + i * 4096 + wid * 1024);
        }
#pragma unroll
        for (int i = 0; i < 2; ++i) {
            int row = i * 32 + srow;
            int cb = (schk ^ (row & 7)) * 8;
            gload_lds16(WfnT + (size_t)(n0 + row) * K + k0 + cb,
                        (char*)Bs + i * 4096 + wid * 1024);
        }
        __syncthreads();
#pragma unroll
        for (int kk = 0; kk < 2; ++kk) {
            const int kc = kk * 4 + (lane >> 4);
            bf16x8 af[2], bfr[4];
#pragma unroll
            for (int i = 0; i < 2; ++i) {
                int row = wid * 32 + i * 16 + (lane & 15);
                af[i] = *(const bf16x8*)(AsB + row * 128 + ((kc ^ (row & 7)) << 4));
            }
#pragma unroll
            for (int j = 0; j < 4; ++j) {
                int col = j * 16 + (lane & 15);
                bfr[j] = *(const bf16x8*)(BsB + col * 128 + ((kc ^ (col & 7)) << 4));
            }
#pragma unroll
            for (int i = 0; i < 2; ++i)
#pragma unroll
                for (int j = 0; j < 4; ++j)
                    acc[i][j] = __builtin_amdgcn_mfma_f32_16x16x32_bf16(af[i], bfr[j], acc[i][j], 0, 0, 0);
        }
        __syncthreads();
    }

    if (n0 < 256) {
#pragma unroll
        for (int i = 0; i < 2; ++i)
#pragma unroll
            for (int j = 0; j < 4; ++j)
#pragma unroll
                for (int q = 0; q < 4; ++q) {
                    int row = m0 + wid * 32 + i * 16 + (lane >> 4) * 4 + q;
                    int col = n0 + j * 16 + (lane & 15);
                    node_proj_s[(size_t)row * P_DIM + col] =
                        exp2c((acc[i][j][q] + biasF[col]) * TANH_C);
                }
    } else {
#pragma unroll
        for (int i = 0; i < 2; ++i)
#pragma unroll
            for (int j = 0; j < 4; ++j)
#pragma unroll
                for (int q = 0; q < 4; ++q) {
                    int row = m0 + wid * 32 + i * 16 + (lane >> 4) * 4 + q;
                    int col = n0 - 256 + j * 16 + (lane & 15);
                    A2[(size_t)row * A2_LD + H1_OFF + col] = f2bf(acc[i][j][q] + biasN[col]);
                }
    }
}

// ======== k4: att+imgz (3072 blocks, nlist order). No barrier: red[wv] wave-private ====
// u_c = Enp_c * Eip_c + 1; sum_c wa_c/u_c via 4-way fraction combine.
// __launch_bounds__(256,4): allow ~64 VGPR so the unrolled 36-region loop can
// software-pipeline (R21's 28-VGPR allocation serialized the shfl chains).
__global__ __launch_bounds__(256, 4) void k4_att(
    const float* __restrict__ Enp, const ushort* __restrict__ Eip,
    const int* __restrict__ batch_ids, const float* __restrict__ Wa,
    const ushort* __restrict__ Z, ushort* __restrict__ imgz,
    const int* __restrict__ nlist)
{
    __shared__ float red[4][R_REG][20];
    const int lane = threadIdx.x & 63;
    const int wv = threadIdx.x >> 6;
    const int n = nlist[blockIdx.x * 4 + wv];   // batch-grouped order
    const int b = batch_ids[n];

    const float4 en = *(const float4*)(Enp + (size_t)n * P_DIM + 4 * lane);
    const float4 wa = *(const float4*)(Wa + 4 * lane);
    const ushort* ip0 = Eip + (size_t)b * R_REG * P_DIM + 4 * lane;

#pragma unroll
    for (int r = 0; r < R_REG; ++r) {
        ushort4v ip = *(const ushort4v*)(ip0 + (size_t)r * P_DIM);
        float u0 = fmaf(en.x, bf2f(ip[0]), 1.f);
        float u1 = fmaf(en.y, bf2f(ip[1]), 1.f);
        float u2 = fmaf(en.z, bf2f(ip[2]), 1.f);
        float u3 = fmaf(en.w, bf2f(ip[3]), 1.f);
        float p01 = u0 * u1, p23 = u2 * u3;
        float n01 = fmaf(wa.x, u1, wa.y * u0);
        float n23 = fmaf(wa.z, u3, wa.w * u2);
        float N = fmaf(n01, p23, n23 * p01);
        float p = N * frcp(p01 * p23);
        p += __shfl_xor(p, 16);
        p += __shfl_xor(p, 32);
        if (lane < 16) red[wv][r][lane] = p;
    }
    // (no __syncthreads: red[wv] is wave-private; within-wave lgkmcnt ordering suffices)

    float logit = -INFINITY;
    if (lane < R_REG) {
        const float* row = &red[wv][lane][0];
        float4 a = *(const float4*)row;
        float4 bq = *(const float4*)(row + 4);
        float4 c = *(const float4*)(row + 8);
        float4 d = *(const float4*)(row + 12);
        float s01 = ((a.x + a.y) + (a.z + a.w)) + ((bq.x + bq.y) + (bq.z + bq.w));
        float s23 = ((c.x + c.y) + (c.z + c.w)) + ((d.x + d.y) + (d.z + d.w));
        logit = -2.f * (s01 + s23);
    }
    float m = logit;
#pragma unroll
    for (int o = 32; o; o >>= 1) m = fmaxf(m, __shfl_xor(m, o));
    float e = (lane < R_REG) ? __expf(logit - m) : 0.f;
    float s = e;
#pragma unroll
    for (int o = 32; o; o >>= 1) s += __shfl_xor(s, o);
    float inv_s = frcp(s);
    if (lane < R_REG) red[wv][lane][16] = e * inv_s;

    // ---- imgz[n] = sum_r att[r] * Z[b][r][:]; lane owns 8 cols ----
    float az[8] = {};
    const ushort* zb = Z + (size_t)b * R_REG * DD_OUT + lane * 8;
#pragma unroll 4
    for (int r = 0; r < R_REG; ++r) {
        uint4 zv = *(const uint4*)(zb + (size_t)r * DD_OUT);
        float a = red[wv][r][16];
        az[0] = fmaf(a, bf2f((ushort)(zv.x & 0xffffu)), az[0]);
        az[1] = fmaf(a, bf2f((ushort)(zv.x >> 16)),     az[1]);
        az[2] = fmaf(a, bf2f((ushort)(zv.y & 0xffffu)), az[2]);
        az[3] = fmaf(a, bf2f((ushort)(zv.y >> 16)),     az[3]);
        az[4] = fmaf(a, bf2f((ushort)(zv.z & 0xffffu)), az[4]);
        az[5] = fmaf(a, bf2f((ushort)(zv.z >> 16)),     az[5]);
        az[6] = fmaf(a, bf2f((ushort)(zv.w & 0xffffu)), az[6]);
        az[7] = fmaf(a, bf2f((ushort)(zv.w >> 16)),     az[7]);
    }
    ushort8v zo;
#pragma unroll
    for (int i = 0; i < 8; ++i) zo[i] = f2bf(az[i]);
    *(ushort8v*)(imgz + (size_t)n * DD_OUT + lane * 8) = zo;
}

// ======== k5: CSR gather (direct-scatter layout): wave per node, 4 loads in flight ====
__device__ __forceinline__ void acc8(float* a, uint4 v) {
    a[0] += bf2f((ushort)(v.x & 0xffffu)); a[1] += bf2f((ushort)(v.x >> 16));
    a[2] += bf2f((ushort)(v.y & 0xffffu)); a[3] += bf2f((ushort)(v.y >> 16));
    a[4] += bf2f((ushort)(v.z & 0xffffu)); a[5] += bf2f((ushort)(v.z >> 16));
    a[6] += bf2f((ushort)(v.w & 0xffffu)); a[7] += bf2f((ushort)(v.w >> 16));
}

__global__ __launch_bounds__(256) void k5_gather(
    const int* __restrict__ cur, const int* __restrict__ ssrc2,
    const ushort* __restrict__ A2h1, ushort* __restrict__ A2nb)
{
    const int lane = threadIdx.x & 63;
    const int wv = threadIdx.x >> 6;
    const int n = blockIdx.x * 4 + wv;
    int dcnt = cur[n];
    if (dcnt > MAXD) dcnt = MAXD;
    const int* es = ssrc2 + (size_t)n * MAXD;

    float a[8] = {};
    int e = 0;
    for (; e + 4 <= dcnt; e += 4) {
        int s0 = es[e], s1 = es[e + 1], s2 = es[e + 2], s3 = es[e + 3];
        uint4 v0 = *(const uint4*)(A2h1 + (size_t)s0 * A2_LD + lane * 8);
        uint4 v1 = *(const uint4*)(A2h1 + (size_t)s1 * A2_LD + lane * 8);
        uint4 v2 = *(const uint4*)(A2h1 + (size_t)s2 * A2_LD + lane * 8);
        uint4 v3 = *(const uint4*)(A2h1 + (size_t)s3 * A2_LD + lane * 8);
        acc8(a, v0); acc8(a, v1); acc8(a, v2); acc8(a, v3);
    }
    for (; e < dcnt; ++e) {
        int s0 = es[e];
        uint4 v0 = *(const uint4*)(A2h1 + (size_t)s0 * A2_LD + lane * 8);
        acc8(a, v0);
    }
    ushort8v o;
#pragma unroll
    for (int i = 0; i < 8; ++i) o[i] = f2bf(a[i]);
    *(ushort8v*)(A2nb + (size_t)n * A2_LD + lane * 8) = o;
}

// ======== k6: final GEMM: out = relu(A2 @ BT2^T + imgz + b'), BM=128 BN=64, K=1024 ====
__global__ __launch_bounds__(256) void gemm_out(
    const ushort* __restrict__ A, const ushort* __restrict__ BT,
    const float* __restrict__ bias, const ushort* __restrict__ Cadd,
    float* __restrict__ Cf)
{
    __shared__ ushort As[128 * 64];
    __shared__ ushort Bs[64 * 64];
    const int K = A2_LD;
    const int tid = threadIdx.x;
    const int lane = tid & 63;
    const int wid = tid >> 6;
    const int lin = xcd_swz(blockIdx.y * 8 + blockIdx.x, 768);
    const int m0 = (lin >> 3) * 128, n0 = (lin & 7) * 64;

    f32x4 acc[2][4] = {};
    const int srow = tid >> 3;
    const int schk = tid & 7;
    const char* AsB = (const char*)As;
    const char* BsB = (const char*)Bs;

    for (int k0 = 0; k0 < K; k0 += 64) {
#pragma unroll
        for (int i = 0; i < 4; ++i) {
            int row = i * 32 + srow;
            int ca = (schk ^ (row & 7)) * 8;
            gload_lds16(A + (size_t)(m0 + row) * K + k0 + ca,
                        (char*)As + i * 4096 + wid * 1024);
        }
#pragma unroll
        for (int i = 0; i < 2; ++i) {
            int row = i * 32 + srow;
            int cb = (schk ^ (row & 7)) * 8;
            gload_lds16(BT + (size_t)(n0 + row) * K + k0 + cb,
                        (char*)Bs + i * 4096 + wid * 1024);
        }
        __syncthreads();
#pragma unroll
        for (int kk = 0; kk < 2; ++kk) {
            const int kc = kk * 4 + (lane >> 4);
            bf16x8 af[2], bfr[4];
#pragma unroll
            for (int i = 0; i < 2; ++i) {
                int row = wid * 32 + i * 16 + (lane & 15);
                af[i] = *(const bf16x8*)(AsB + row * 128 + ((kc ^ (row & 7)) << 4));
            }
#pragma unroll
            for (int j = 0; j < 4; ++j) {
                int col = j * 16 + (lane & 15);
                bfr[j] = *(const bf16x8*)(BsB + col * 128 + ((kc ^ (col & 7)) << 4));
            }
#pragma unroll
            for (int i = 0; i < 2; ++i)
#pragma unroll
                for (int j = 0; j < 4; ++j)
                    acc[i][j] = __builtin_amdgcn_mfma_f32_16x16x32_bf16(af[i], bfr[j], acc[i][j], 0, 0, 0);
        }
        __syncthreads();
    }

#pragma unroll
    for (int i = 0; i < 2; ++i)
#pragma unroll
        for (int j = 0; j < 4; ++j)
#pragma unroll
            for (int q = 0; q < 4; ++q) {
                int row = m0 + wid * 32 + i * 16 + (lane >> 4) * 4 + q;
                int col = n0 + j * 16 + (lane & 15);
                float v = acc[i][j][q] + bias[col] + bf2f(Cadd[(size_t)row * DD_OUT + col]);
                Cf[(size_t)row * DD_OUT + col] = fmaxf(v, 0.f);
            }
}

extern "C" void kernel_launch(void* const* d_in, const int* in_sizes, int n_in,
                              void* d_out, int out_size, void* d_ws, size_t ws_size,
                              hipStream_t stream) {
    const float* h         = (const float*)d_in[0];
    const float* img_feats = (const float*)d_in[1];
    const int*   batch_ids = (const int*)d_in[2];
    const int*   src       = (const int*)d_in[3];
    const int*   dst       = (const int*)d_in[4];
    const float* Wf  = (const float*)d_in[5];
    const float* bf  = (const float*)d_in[6];
    const float* Wi  = (const float*)d_in[7];
    const float* bi  = (const float*)d_in[8];
    const float* Wa  = (const float*)d_in[9];
    // d_in[10] = ba: constant logit shift, cancels in softmax
    const float* Wn  = (const float*)d_in[11];
    const float* bn  = (const float*)d_in[12];
    const float* Wim = (const float*)d_in[13];
    const float* bim = (const float*)d_in[14];
    const float* Wap = (const float*)d_in[15];
    const float* bap = (const float*)d_in[16];
    float* out = (float*)d_out;
    float* ws  = (float*)d_ws;

    // ---- workspace layout (offsets in 4-byte words) ----
    ushort* A2      = (ushort*)(ws + 0);          // [12288][1024] bf16: neigh|h1
    ushort* imgz    = (ushort*)(ws + 6291456);    // [12288][512] bf16
    float*  node_proj = ws + 9437184;             // [12288][256] f32 = Enp (exp2 form)
    ushort* img_projb = (ushort*)(ws + 12582912); // [2304][256] bf16 = Eip (exp2 form)
    ushort* Z      = (ushort*)(ws + 12877824);    // [2304][512] bf16
    ushort* h_bf   = (ushort*)(ws + 13467648);    // [12288][512] bf16
    ushort* WfnT   = (ushort*)(ws + 16613376);    // [768][512] bf16
    ushort* WiZT   = (ushort*)(ws + 16809984);    // [768][1024] bf16: Wi^T | W'^T
    ushort* Wap1T  = (ushort*)(ws + 17203200);    // [512][512] bf16
    ushort* BT2    = (ushort*)(ws + 17334272);    // [512][1024] bf16: Wap1^T | Wap2^T
    float*  bprime = ws + 17596416;               // [512]
    int* cur   = (int*)(ws + 17596928);           // [12288] (zeroed; becomes degree)
    int* nlist = cur + N_NODES;                   // [12288]
    int* ssrc2 = nlist + N_NODES;                 // [12288 * MAXD]

    dim3 blk(256);

    // k1: h cvt + weight transposes + zero cur
    preamble<<<dim3(PCVT_BLKS + TR_BLKS + ZERO_BLKS), blk, 0, stream>>>(
        h, h_bf, Wf, Wn, Wi, Wap, WfnT, WiZT, Wap1T, BT2, cur);
    // k2: direct edge scatter || batch sort -> nlist || wp GEMM
    k2_scatter_sort_wp<<<dim3(ECNT_BLKS + 1 + 32), blk, 0, stream>>>(
        src, dst, batch_ids, cur, ssrc2, nlist, Wap1T, Wim, WiZT);
    // k3: bprime || imgz GEMM (exp2 epilogue) || ff GEMM (exp2 epilogue)
    k3_imgz_ff<<<dim3(FF_BASE + 1152), blk, 0, stream>>>(
        bim, Wap, bap, bprime,
        img_feats, WiZT, bi, img_projb, Z,
        h_bf, WfnT, bf, bn, node_proj, A2);
    // k4: att+imgz (1 node/wave, nlist order, no barrier, relaxed reg budget)
    k4_att<<<dim3(N_NODES / 4), blk, 0, stream>>>(
        node_proj, img_projb, batch_ids, Wa, Z, imgz, nlist);
    // k5: CSR gather -> A2 neigh cols
    k5_gather<<<dim3(N_NODES / 4), blk, 0, stream>>>(
        cur, ssrc2, A2 + H1_OFF, A2 + NEIGH_OFF);
    // k6: out = relu(A2 @ [Wap1; Wap2] + imgz + b')
    gemm_out<<<dim3(8, 96), blk, 0, stream>>>(A2, BT2, bprime, imgz, out);
}